// Round 4
// baseline (1692.170 us; speedup 1.0000x reference)
//
#include <hip/hip_runtime.h>
#include <hip/hip_bf16.h>
#include <math.h>

#define BSHIFT 7                 // 128 nodes per bucket
#define NBUCK(N) (((N) + 127) >> 7)
#define TILE 8192                // edges per partition block (R0's proven value)
#define CAP 5632                 // max edges/bucket (mean 4224, sd ~65 -> ~21 sigma)

typedef short bf16x8 __attribute__((ext_vector_type(8)));
typedef float f32x16 __attribute__((ext_vector_type(16)));

// ---- bf16 helpers ---------------------------------------------------------
__device__ __forceinline__ unsigned short f2bf(float f) {
    unsigned u = __float_as_uint(f);
    u += 0x7fffu + ((u >> 16) & 1u);      // RNE
    return (unsigned short)(u >> 16);
}
__device__ __forceinline__ unsigned packbf2(float lo, float hi) {
    return (unsigned)f2bf(lo) | ((unsigned)f2bf(hi) << 16);
}
__device__ __forceinline__ float bf_lo(unsigned u) { return __uint_as_float(u << 16); }
__device__ __forceinline__ float bf_hi(unsigned u) { return __uint_as_float(u & 0xffff0000u); }

// ---- partition: edges -> fixed-stride dst-buckets & src-buckets -----------
// EXACT R0 form (measured 103 us): TILE=8192, dv[32] in regs, two-sided LDS
// bucket counting. R0-R3 matrix showed: occupancy is NOT the limiter (55% occ
// was slower), per-edge global atomics are a wash, TILE=8192 minimizes
// cross-block partial-line write amplification (160 vs 197 MB).
__global__ __launch_bounds__(256) void part_kernel(
    const int* __restrict__ src, const int* __restrict__ dst,
    int* __restrict__ gcurD, int* __restrict__ gcurS,
    int* __restrict__ gbufD, unsigned char* __restrict__ gbufS, int E, int K) {
    __shared__ int cD[800], bD[800], cS[800], bS[800];   // 12.8 KB
    const int t = threadIdx.x;
    const int tile = blockIdx.x * TILE;
    for (int i = t; i < K; i += 256) { cD[i] = 0; cS[i] = 0; }
    __syncthreads();

    int dv[32];
    #pragma unroll
    for (int i = 0; i < 32; ++i) {
        const int e = tile + i * 256 + t;
        dv[i] = (e < E) ? dst[e] : -1;
        if (dv[i] >= 0) {
            atomicAdd(&cD[dv[i] >> BSHIFT], 1);
            atomicAdd(&cS[src[e] >> BSHIFT], 1);
        }
    }
    __syncthreads();
    for (int i = t; i < K; i += 256) {
        int c = cD[i];
        bD[i] = (c ? atomicAdd(&gcurD[i], c) : 0) + i * CAP;
        cD[i] = 0;
        c = cS[i];
        bS[i] = (c ? atomicAdd(&gcurS[i], c) : 0) + i * CAP;
        cS[i] = 0;
    }
    __syncthreads();
    #pragma unroll
    for (int i = 0; i < 32; ++i) {
        if (dv[i] >= 0) {
            const int e = tile + i * 256 + t;
            const int sv = src[e];
            const int b1 = dv[i] >> BSHIFT;
            const int p1 = bD[b1] + atomicAdd(&cD[b1], 1);
            gbufD[p1] = ((dv[i] & 127) << 17) | sv;
            const int b2 = sv >> BSHIFT;
            const int p2 = bS[b2] + atomicAdd(&cS[b2], 1);
            gbufS[p2] = (unsigned char)(sv & 127);
        }
    }
}

// ---- fillS: per src-bucket (128 nodes): outdeg -> nsrc --------------------
__global__ __launch_bounds__(256) void fillS_kernel(
    const int* __restrict__ cntS, const unsigned char* __restrict__ gbufS,
    float* __restrict__ nsrc, int N, int K) {
    __shared__ int cnt[128];
    const int t = threadIdx.x;
    const int b = blockIdx.x;
    if (t < 128) cnt[t] = 0;
    __syncthreads();
    const int bs = b * CAP;
    const int be = bs + cntS[b];
    for (int idx = bs + t; idx < be; idx += 256)
        atomicAdd(&cnt[gbufS[idx]], 1);
    __syncthreads();
    const int n = (b << BSHIFT) + t;
    if (t < 128 && n < N) nsrc[n] = rsqrtf((float)cnt[t]);   // self-loops => deg>=1
}

// ---- GEMM1 (MFMA): h1[n][j] = bf16( nsrc[n] * sum_k feat[n][k]*W1[k][j] ) -
__global__ __launch_bounds__(256) void gemm1_kernel(
    const float* __restrict__ feat, const float* __restrict__ W1,
    const float* __restrict__ nsrc, unsigned short* __restrict__ h1, int N) {
    __shared__ short W1t[32 * 264];    // 16.9 KB: W1t[c][k] = bf16(W1[k][c])
    const int t = threadIdx.x;
    for (int i = t; i < 8192; i += 256) {
        const int k = i >> 5, c = i & 31;
        W1t[c * 264 + k] = (short)f2bf(W1[i]);
    }
    __syncthreads();

    const int l  = t & 63;
    const int wv = t >> 6;
    const int base = blockIdx.x * 128 + wv * 32;
    const int m  = l & 31;
    const int kh = (l >> 5) << 3;
    int r = base + m;
    if (r >= N) r = N - 1;
    const float* fr = feat + (size_t)r * 256 + kh;
    const short* wr = &W1t[m * 264 + kh];

    f32x16 acc;
    #pragma unroll
    for (int i = 0; i < 16; ++i) acc[i] = 0.f;

    #pragma unroll
    for (int kb = 0; kb < 16; ++kb) {
        const float4 f0 = *(const float4*)(fr + kb * 16);
        const float4 f1 = *(const float4*)(fr + kb * 16 + 4);
        bf16x8 a;
        a[0] = (short)f2bf(f0.x); a[1] = (short)f2bf(f0.y);
        a[2] = (short)f2bf(f0.z); a[3] = (short)f2bf(f0.w);
        a[4] = (short)f2bf(f1.x); a[5] = (short)f2bf(f1.y);
        a[6] = (short)f2bf(f1.z); a[7] = (short)f2bf(f1.w);
        const bf16x8 b = *(const bf16x8*)(wr + kb * 16);
        acc = __builtin_amdgcn_mfma_f32_32x32x16_bf16(a, b, acc, 0, 0, 0);
    }

    const int rbase = base + ((l >> 5) << 2);
    #pragma unroll
    for (int reg = 0; reg < 16; ++reg) {
        const int row = rbase + (reg & 3) + ((reg >> 2) << 3);
        if (row < N)
            h1[(size_t)row * 32 + m] = f2bf(acc[reg] * nsrc[row]);
    }
}

// ---- agg1b: bucket-direct aggregation (replaces fillD+CSR+agg1) -----------
// One block per dst-bucket: 128 nodes x 32 ch fp32 accumulators in LDS
// (+33 pad => bank = (d + ch) & 31, conflict-spread). Consumes gbufD segment
// directly (unsorted) via ds_add_f32; indeg/ndst computed as by-product.
// Deletes fillD dispatch + csr build/read traffic (~66 MB).
__global__ __launch_bounds__(512) void agg1b_kernel(
    const int* __restrict__ cntD, const int* __restrict__ gbufD,
    const unsigned* __restrict__ h1, const float* __restrict__ nsrc,
    const float* __restrict__ b1, unsigned* __restrict__ x1s, int N) {
    __shared__ float acc[128 * 33];   // 16.9 KB
    __shared__ int cnt[128];
    __shared__ float sb1[32];
    const int t = threadIdx.x;
    const int b = blockIdx.x;
    for (int i = t; i < 128 * 33; i += 512) acc[i] = 0.f;
    if (t < 128) cnt[t] = 0;
    if (t >= 128 && t < 160) sb1[t - 128] = b1[t - 128];
    __syncthreads();

    const int bs = b * CAP;
    const int be = bs + cntD[b];
    const int c = t & 3;
    const uint4* H = (const uint4*)h1;
    for (int idx = bs + (t >> 2); idx < be; idx += 128) {
        const int p = gbufD[idx];
        const int s = p & 131071;
        const int d = p >> 17;
        const uint4 q = H[(size_t)s * 4 + c];
        float* ap = &acc[d * 33 + c * 8];
        atomicAdd(ap + 0, bf_lo(q.x)); atomicAdd(ap + 1, bf_hi(q.x));
        atomicAdd(ap + 2, bf_lo(q.y)); atomicAdd(ap + 3, bf_hi(q.y));
        atomicAdd(ap + 4, bf_lo(q.z)); atomicAdd(ap + 5, bf_hi(q.z));
        atomicAdd(ap + 6, bf_lo(q.w)); atomicAdd(ap + 7, bf_hi(q.w));
        if (c == 0) atomicAdd(&cnt[d], 1);
    }
    __syncthreads();

    if (t < 128) {
        const int n = (b << BSHIFT) + t;
        if (n < N) {
            const float nd = rsqrtf((float)cnt[t]);   // self-loops => cnt>=1
            const float ns = nsrc[n];
            const float* ar = &acc[t * 33];
            unsigned o[16];
            #pragma unroll
            for (int j = 0; j < 16; ++j) {
                const float lo = fmaxf(ar[2 * j]     * nd + sb1[2 * j],     0.f) * ns;
                const float hi = fmaxf(ar[2 * j + 1] * nd + sb1[2 * j + 1], 0.f) * ns;
                o[j] = packbf2(lo, hi);
            }
            uint4* X = (uint4*)x1s + (size_t)n * 4;
            X[0] = ((uint4*)o)[0]; X[1] = ((uint4*)o)[1];
            X[2] = ((uint4*)o)[2]; X[3] = ((uint4*)o)[3];
        }
    }
}

// ---- agg2b: bucket-direct agg + W2 matvec + log_softmax (fused final) -----
// Same LDS-accumulate structure; epilogue: 2 threads/node compute 20 logits
// each from the LDS acc row, softmax-reduce via shfl_xor(1).
__global__ __launch_bounds__(512) void agg2b_kernel(
    const int* __restrict__ cntD, const int* __restrict__ gbufD,
    const unsigned* __restrict__ x1s, const float* __restrict__ W2,
    const float* __restrict__ b2, float* __restrict__ out, int N) {
    __shared__ float acc[128 * 33];   // 16.9 KB
    __shared__ int cnt[128];
    __shared__ float sW2[1280];       // 5.1 KB
    __shared__ float sb2[40];
    const int t = threadIdx.x;
    const int b = blockIdx.x;
    for (int i = t; i < 128 * 33; i += 512) acc[i] = 0.f;
    for (int i = t; i < 1280; i += 512) sW2[i] = W2[i];
    if (t < 128) cnt[t] = 0;
    if (t >= 128 && t < 168) sb2[t - 128] = b2[t - 128];
    __syncthreads();

    const int bs = b * CAP;
    const int be = bs + cntD[b];
    const int c = t & 3;
    const uint4* H = (const uint4*)x1s;
    for (int idx = bs + (t >> 2); idx < be; idx += 128) {
        const int p = gbufD[idx];
        const int s = p & 131071;
        const int d = p >> 17;
        const uint4 q = H[(size_t)s * 4 + c];
        float* ap = &acc[d * 33 + c * 8];
        atomicAdd(ap + 0, bf_lo(q.x)); atomicAdd(ap + 1, bf_hi(q.x));
        atomicAdd(ap + 2, bf_lo(q.y)); atomicAdd(ap + 3, bf_hi(q.y));
        atomicAdd(ap + 4, bf_lo(q.z)); atomicAdd(ap + 5, bf_hi(q.z));
        atomicAdd(ap + 6, bf_lo(q.w)); atomicAdd(ap + 7, bf_hi(q.w));
        if (c == 0) atomicAdd(&cnt[d], 1);
    }
    __syncthreads();

    if (t < 256) {
        const int node = t >> 1, sub = t & 1;
        const int n = (b << BSHIFT) + node;
        if (n < N) {
            const float nd = rsqrtf((float)cnt[node]);
            const float* ar = &acc[node * 33];
            float z[20];
            #pragma unroll
            for (int u = 0; u < 20; ++u) z[u] = sb2[sub * 20 + u];
            #pragma unroll
            for (int k = 0; k < 32; ++k) {
                const float v = ar[k] * nd;
                const float* Wr = &sW2[k * 40 + sub * 20];
                #pragma unroll
                for (int u = 0; u < 20; ++u) z[u] += v * Wr[u];
            }
            float m = z[0];
            #pragma unroll
            for (int u = 1; u < 20; ++u) m = fmaxf(m, z[u]);
            m = fmaxf(m, __shfl_xor(m, 1, 64));
            float s = 0.f;
            #pragma unroll
            for (int u = 0; u < 20; ++u) s += __expf(z[u] - m);
            s += __shfl_xor(s, 1, 64);
            const float ls = __logf(s);
            float* op = out + (size_t)n * 40 + sub * 20;
            #pragma unroll
            for (int u = 0; u < 20; ++u) op[u] = z[u] - m - ls;
        }
    }
}

extern "C" void kernel_launch(void* const* d_in, const int* in_sizes, int n_in,
                              void* d_out, int out_size, void* d_ws, size_t ws_size,
                              hipStream_t stream) {
    const float* feat = (const float*)d_in[0];
    const int*   src  = (const int*)d_in[1];
    const int*   dst  = (const int*)d_in[2];
    const float* W1   = (const float*)d_in[3];
    const float* b1   = (const float*)d_in[4];
    const float* W2   = (const float*)d_in[5];
    const float* b2   = (const float*)d_in[6];
    float* out = (float*)d_out;

    const int N = in_sizes[0] / 256;   // 100000
    const int E = in_sizes[1];         // 3300000
    const int K = NBUCK(N);            // 782 buckets of 128 nodes

    // layout (~30.8 MB): gbufD is now DEDICATED -- it must stay valid through
    // BOTH agg passes (it IS the edge list; csr/fillD deleted). gbufS (4.4 MB,
    // dead after fillS) overlays x1s (6.4 MB, first written by agg1b).
    char* p = (char*)d_ws;
    float* nsrc = (float*)p;                 p += (size_t)N * 4;        // 400 KB
    unsigned* h1  = (unsigned*)p;            p += (size_t)N * 64;       // 6.4 MB
    unsigned* x1s = (unsigned*)p;            p += (size_t)N * 64;       // 6.4 MB
    int* gbufD    = (int*)p;                 p += (size_t)K * CAP * 4;  // 17.6 MB
    int* gcurD    = (int*)p;                 p += 800 * 4;
    int* gcurS    = (int*)p;                 p += 800 * 4;
    unsigned char* gbufS = (unsigned char*)x1s;   // overlay, dead after fillS

    hipMemsetAsync(gcurD, 0, sizeof(int) * 1600, stream);  // gcurD + gcurS

    const int PB = (E + TILE - 1) / TILE;

    part_kernel<<<PB, 256, 0, stream>>>(src, dst, gcurD, gcurS, gbufD, gbufS, E, K);
    fillS_kernel<<<K, 256, 0, stream>>>(gcurS, gbufS, nsrc, N, K);

    gemm1_kernel<<<(N + 127) / 128, 256, 0, stream>>>(feat, W1, nsrc, (unsigned short*)h1, N);
    agg1b_kernel<<<K, 512, 0, stream>>>(gcurD, gbufD, h1, nsrc, b1, x1s, N);
    agg2b_kernel<<<K, 512, 0, stream>>>(gcurD, gbufD, x1s, W2, b2, out, N);
}

// Round 5
// 449.625 us; speedup vs baseline: 3.7635x; 3.7635x over previous
//
#include <hip/hip_runtime.h>
#include <hip/hip_bf16.h>
#include <math.h>

#define BSHIFT 7                 // 128 nodes per bucket
#define NBUCK(N) (((N) + 127) >> 7)
#define TILE 8192                // edges per partition block (R0 proven: 103 us)
#define CAP 5632                 // max edges/bucket (mean 4224, sd ~65 -> ~21 sigma)

typedef short bf16x8 __attribute__((ext_vector_type(8)));
typedef float f32x16 __attribute__((ext_vector_type(16)));

// ---- bf16 helpers ---------------------------------------------------------
__device__ __forceinline__ unsigned short f2bf(float f) {
    unsigned u = __float_as_uint(f);
    u += 0x7fffu + ((u >> 16) & 1u);      // RNE
    return (unsigned short)(u >> 16);
}
__device__ __forceinline__ unsigned packbf2(float lo, float hi) {
    return (unsigned)f2bf(lo) | ((unsigned)f2bf(hi) << 16);
}
__device__ __forceinline__ float bf_lo(unsigned u) { return __uint_as_float(u << 16); }
__device__ __forceinline__ float bf_hi(unsigned u) { return __uint_as_float(u & 0xffff0000u); }

// ---- partition: edges -> fixed-stride dst-buckets & src-buckets -----------
// EXACT R0 form (measured 103 us). R0-R4 matrix: occupancy is NOT the limiter
// (55% occ was slower), per-edge global atomics are a wash, TILE=8192
// minimizes cross-block partial-line write amplification (160 vs 197 MB).
__global__ __launch_bounds__(256) void part_kernel(
    const int* __restrict__ src, const int* __restrict__ dst,
    int* __restrict__ gcurD, int* __restrict__ gcurS,
    int* __restrict__ gbufD, unsigned char* __restrict__ gbufS, int E, int K) {
    __shared__ int cD[800], bD[800], cS[800], bS[800];   // 12.8 KB
    const int t = threadIdx.x;
    const int tile = blockIdx.x * TILE;
    for (int i = t; i < K; i += 256) { cD[i] = 0; cS[i] = 0; }
    __syncthreads();

    int dv[32];
    #pragma unroll
    for (int i = 0; i < 32; ++i) {
        const int e = tile + i * 256 + t;
        dv[i] = (e < E) ? dst[e] : -1;
        if (dv[i] >= 0) {
            atomicAdd(&cD[dv[i] >> BSHIFT], 1);
            atomicAdd(&cS[src[e] >> BSHIFT], 1);
        }
    }
    __syncthreads();
    for (int i = t; i < K; i += 256) {
        int c = cD[i];
        bD[i] = (c ? atomicAdd(&gcurD[i], c) : 0) + i * CAP;
        cD[i] = 0;
        c = cS[i];
        bS[i] = (c ? atomicAdd(&gcurS[i], c) : 0) + i * CAP;
        cS[i] = 0;
    }
    __syncthreads();
    #pragma unroll
    for (int i = 0; i < 32; ++i) {
        if (dv[i] >= 0) {
            const int e = tile + i * 256 + t;
            const int sv = src[e];
            const int b1 = dv[i] >> BSHIFT;
            const int p1 = bD[b1] + atomicAdd(&cD[b1], 1);
            gbufD[p1] = ((dv[i] & 127) << 17) | sv;
            const int b2 = sv >> BSHIFT;
            const int p2 = bS[b2] + atomicAdd(&cS[b2], 1);
            gbufS[p2] = (unsigned char)(sv & 127);
        }
    }
}

// ---- fillS: per src-bucket (128 nodes): outdeg -> nsrc --------------------
__global__ __launch_bounds__(256) void fillS_kernel(
    const int* __restrict__ cntS, const unsigned char* __restrict__ gbufS,
    float* __restrict__ nsrc, int N, int K) {
    __shared__ int cnt[128];
    const int t = threadIdx.x;
    const int b = blockIdx.x;
    if (t < 128) cnt[t] = 0;
    __syncthreads();
    const int bs = b * CAP;
    const int be = bs + cntS[b];
    for (int idx = bs + t; idx < be; idx += 256)
        atomicAdd(&cnt[gbufS[idx]], 1);
    __syncthreads();
    const int n = (b << BSHIFT) + t;
    if (t < 128 && n < N) nsrc[n] = rsqrtf((float)cnt[t]);   // self-loops => deg>=1
}

// ---- fillD: per dst-bucket (128 nodes): indeg, rowstart, ndst, CSR --------
// Scattered csr writes confined to this block's 22 KB window -> full-line
// merges in one XCD L2. (R4 showed the CSR is worth its traffic: it breaks
// the agg kernels' dependent-load chain.)
__global__ __launch_bounds__(256) void fillD_kernel(
    const int* __restrict__ cntD, const int* __restrict__ gbufD,
    int* __restrict__ csr_src, int* __restrict__ rowstart, int* __restrict__ indeg,
    float* __restrict__ ndst, int N, int K) {
    __shared__ int cnt[128];
    __shared__ int sc[128];
    __shared__ int cur[128];
    const int t = threadIdx.x;
    const int b = blockIdx.x;
    if (t < 128) cnt[t] = 0;
    __syncthreads();
    const int bs = b * CAP;
    const int be = bs + cntD[b];
    for (int idx = bs + t; idx < be; idx += 256)
        atomicAdd(&cnt[gbufD[idx] >> 17], 1);
    __syncthreads();
    if (t < 128) sc[t] = cnt[t];
    __syncthreads();
    for (int off = 1; off < 128; off <<= 1) {
        int x = (t < 128 && t >= off) ? sc[t - off] : 0;
        __syncthreads();
        if (t < 128) sc[t] += x;
        __syncthreads();
    }
    if (t < 128) {
        const int deg = cnt[t];
        const int rs = bs + sc[t] - deg;
        cur[t] = rs;
        const int n = (b << BSHIFT) + t;
        if (n < N) {
            rowstart[n] = rs;
            indeg[n] = deg;
            ndst[n] = rsqrtf((float)deg);   // self-loops => deg >= 1
        }
    }
    __syncthreads();
    for (int idx = bs + t; idx < be; idx += 256) {
        const int p = gbufD[idx];
        const int pos = atomicAdd(&cur[p >> 17], 1);
        csr_src[pos] = p & 131071;
    }
}

// ---- GEMM1 (MFMA): h1[n][j] = bf16( nsrc[n] * sum_k feat[n][k]*W1[k][j] ) -
__global__ __launch_bounds__(256) void gemm1_kernel(
    const float* __restrict__ feat, const float* __restrict__ W1,
    const float* __restrict__ nsrc, unsigned short* __restrict__ h1, int N) {
    __shared__ short W1t[32 * 264];    // 16.9 KB: W1t[c][k] = bf16(W1[k][c])
    const int t = threadIdx.x;
    for (int i = t; i < 8192; i += 256) {
        const int k = i >> 5, c = i & 31;
        W1t[c * 264 + k] = (short)f2bf(W1[i]);
    }
    __syncthreads();

    const int l  = t & 63;
    const int wv = t >> 6;
    const int base = blockIdx.x * 128 + wv * 32;
    const int m  = l & 31;
    const int kh = (l >> 5) << 3;
    int r = base + m;
    if (r >= N) r = N - 1;
    const float* fr = feat + (size_t)r * 256 + kh;
    const short* wr = &W1t[m * 264 + kh];

    f32x16 acc;
    #pragma unroll
    for (int i = 0; i < 16; ++i) acc[i] = 0.f;

    #pragma unroll
    for (int kb = 0; kb < 16; ++kb) {
        const float4 f0 = *(const float4*)(fr + kb * 16);
        const float4 f1 = *(const float4*)(fr + kb * 16 + 4);
        bf16x8 a;
        a[0] = (short)f2bf(f0.x); a[1] = (short)f2bf(f0.y);
        a[2] = (short)f2bf(f0.z); a[3] = (short)f2bf(f0.w);
        a[4] = (short)f2bf(f1.x); a[5] = (short)f2bf(f1.y);
        a[6] = (short)f2bf(f1.z); a[7] = (short)f2bf(f1.w);
        const bf16x8 b = *(const bf16x8*)(wr + kb * 16);
        acc = __builtin_amdgcn_mfma_f32_32x32x16_bf16(a, b, acc, 0, 0, 0);
    }

    const int rbase = base + ((l >> 5) << 2);
    #pragma unroll
    for (int reg = 0; reg < 16; ++reg) {
        const int row = rbase + (reg & 3) + ((reg >> 2) << 3);
        if (row < N)
            h1[(size_t)row * 32 + m] = f2bf(acc[reg] * nsrc[row]);
    }
}

// ---- agg1: x1s[n] = bf16( relu(ndst[n]*sum h1[src] + b1) * nsrc[n] ) ------
// 64 nodes/block, 4 lanes/node, register accumulation (the measured-fast form).
__global__ __launch_bounds__(256) void agg1_kernel(
    const int* __restrict__ csr_src, const int* __restrict__ rowstart,
    const int* __restrict__ indeg, const unsigned* __restrict__ h1,
    const float* __restrict__ ndst, const float* __restrict__ nsrc,
    const float* __restrict__ b1, unsigned* __restrict__ x1s, int N) {
    const int t = threadIdx.x;
    const int n = blockIdx.x * 64 + (t >> 2);
    if (n >= N) return;
    const int c = t & 3;
    const int rs = rowstart[n];
    const int re = rs + indeg[n];
    float a0=0.f,a1=0.f,a2=0.f,a3=0.f,a4=0.f,a5=0.f,a6=0.f,a7=0.f;
    const uint4* H = (const uint4*)h1;
    for (int k = rs; k < re; ++k) {
        const int s = csr_src[k];
        const uint4 q = H[(size_t)s * 4 + c];
        a0 += bf_lo(q.x); a1 += bf_hi(q.x);
        a2 += bf_lo(q.y); a3 += bf_hi(q.y);
        a4 += bf_lo(q.z); a5 += bf_hi(q.z);
        a6 += bf_lo(q.w); a7 += bf_hi(q.w);
    }
    const float nd = ndst[n];
    const float ns = nsrc[n];
    const float* bb = b1 + c * 8;
    float x0 = fmaxf(a0 * nd + bb[0], 0.f) * ns;
    float x1 = fmaxf(a1 * nd + bb[1], 0.f) * ns;
    float x2 = fmaxf(a2 * nd + bb[2], 0.f) * ns;
    float x3 = fmaxf(a3 * nd + bb[3], 0.f) * ns;
    float x4 = fmaxf(a4 * nd + bb[4], 0.f) * ns;
    float x5 = fmaxf(a5 * nd + bb[5], 0.f) * ns;
    float x6 = fmaxf(a6 * nd + bb[6], 0.f) * ns;
    float x7 = fmaxf(a7 * nd + bb[7], 0.f) * ns;
    uint4 o;
    o.x = packbf2(x0, x1); o.y = packbf2(x2, x3);
    o.z = packbf2(x4, x5); o.w = packbf2(x6, x7);
    ((uint4*)x1s)[(size_t)n * 4 + c] = o;
}

// ---- agg2+final fused: z = (ndst[n]*sum x1s[src]) @ W2 + b2; log_softmax --
// a2 round-trip (12.8 MB write + 12.8 MB read) and one dispatch removed.
// The 32->40 matvec runs in-register within each 4-lane node group via shfl;
// softmax reduces over {10 local values} x {4 lanes} with two shfl_xor.
__global__ __launch_bounds__(256) void agg2f_kernel(
    const int* __restrict__ csr_src, const int* __restrict__ rowstart,
    const int* __restrict__ indeg, const unsigned* __restrict__ x1s,
    const float* __restrict__ ndst, const float* __restrict__ W2,
    const float* __restrict__ b2, float* __restrict__ out, int N) {
    __shared__ float sW2[32 * 40];
    __shared__ float sb2[40];
    const int t = threadIdx.x;
    for (int i = t; i < 1280; i += 256) sW2[i] = W2[i];
    if (t < 40) sb2[t] = b2[t];
    __syncthreads();
    const int n = blockIdx.x * 64 + (t >> 2);
    if (n >= N) return;
    const int c = t & 3;
    const int rs = rowstart[n];
    const int re = rs + indeg[n];
    float a0=0.f,a1=0.f,a2=0.f,a3=0.f,a4=0.f,a5=0.f,a6=0.f,a7=0.f;
    const uint4* H = (const uint4*)x1s;
    for (int k = rs; k < re; ++k) {
        const int s = csr_src[k];
        const uint4 q = H[(size_t)s * 4 + c];
        a0 += bf_lo(q.x); a1 += bf_hi(q.x);
        a2 += bf_lo(q.y); a3 += bf_hi(q.y);
        a4 += bf_lo(q.z); a5 += bf_hi(q.z);
        a6 += bf_lo(q.w); a7 += bf_hi(q.w);
    }
    const float nd = ndst[n];
    const float v0 = a0 * nd, v1 = a1 * nd, v2 = a2 * nd, v3 = a3 * nd;
    const float v4 = a4 * nd, v5 = a5 * nd, v6 = a6 * nd, v7 = a7 * nd;

    // lane c holds channels c*8..c*8+7 of this node's a2 row.
    // compute z[j] for j = c*10 .. c*10+9.
    float z[10];
    #pragma unroll
    for (int u = 0; u < 10; ++u) z[u] = sb2[c * 10 + u];
    const int gbase = (t & 63) & ~3;      // wave-lane base of this node's group
    #pragma unroll
    for (int cc = 0; cc < 4; ++cc) {
        const int sl = gbase | cc;
        const float w0 = __shfl(v0, sl, 64);
        const float w1 = __shfl(v1, sl, 64);
        const float w2 = __shfl(v2, sl, 64);
        const float w3 = __shfl(v3, sl, 64);
        const float w4 = __shfl(v4, sl, 64);
        const float w5 = __shfl(v5, sl, 64);
        const float w6 = __shfl(v6, sl, 64);
        const float w7 = __shfl(v7, sl, 64);
        const float* Wr = &sW2[(cc * 8) * 40 + c * 10];
        #pragma unroll
        for (int u = 0; u < 10; ++u) {
            z[u] += w0 * Wr[u]       + w1 * Wr[40 + u]  + w2 * Wr[80 + u]  + w3 * Wr[120 + u]
                  + w4 * Wr[160 + u] + w5 * Wr[200 + u] + w6 * Wr[240 + u] + w7 * Wr[280 + u];
        }
    }
    float m = z[0];
    #pragma unroll
    for (int u = 1; u < 10; ++u) m = fmaxf(m, z[u]);
    m = fmaxf(m, __shfl_xor(m, 1, 64));
    m = fmaxf(m, __shfl_xor(m, 2, 64));
    float s = 0.f;
    #pragma unroll
    for (int u = 0; u < 10; ++u) s += __expf(z[u] - m);
    s += __shfl_xor(s, 1, 64);
    s += __shfl_xor(s, 2, 64);
    const float ls = __logf(s);
    float* op = out + (size_t)n * 40 + c * 10;
    #pragma unroll
    for (int u = 0; u < 10; ++u) op[u] = z[u] - m - ls;
}

extern "C" void kernel_launch(void* const* d_in, const int* in_sizes, int n_in,
                              void* d_out, int out_size, void* d_ws, size_t ws_size,
                              hipStream_t stream) {
    const float* feat = (const float*)d_in[0];
    const int*   src  = (const int*)d_in[1];
    const int*   dst  = (const int*)d_in[2];
    const float* W1   = (const float*)d_in[3];
    const float* b1   = (const float*)d_in[4];
    const float* W2   = (const float*)d_in[5];
    const float* b2   = (const float*)d_in[6];
    float* out = (float*)d_out;

    const int N = in_sizes[0] / 256;   // 100000
    const int E = in_sizes[1];         // 3300000
    const int K = NBUCK(N);            // 782 buckets of 128 nodes

    // layout: byte-identical to the proven R0 layout. a2 region is retained
    // purely as overlay backing for gbufD/gbufS (agg2+final fused; a2 unused).
    char* p = (char*)d_ws;
    float* nsrc = (float*)p;                 p += (size_t)N * 4;        // 400 KB
    float* ndst = (float*)p;                 p += (size_t)N * 4;
    unsigned* h1  = (unsigned*)p;            p += (size_t)N * 64;       // 6.4 MB
    unsigned* x1s = (unsigned*)p;            p += (size_t)N * 64;       // 6.4 MB
    float* a2 = (float*)p;                   p += (size_t)N * 128;      // 12.8 MB (overlay only)
    int* rowstart = (int*)p;                 p += (size_t)N * 4;
    int* indeg_i  = (int*)p;                 p += (size_t)N * 4;
    int* gcurD    = (int*)p;                 p += 800 * 4;
    int* gcurS    = (int*)p;                 p += 800 * 4;
    int* csr_src  = (int*)p;                 p += (size_t)K * CAP * 4;  // 17.6 MB
    (void)a2;
    // transient overlays over [h1, x1s, a2] (25.6 MB dead during CSR build):
    int* gbufD = (int*)h1;                                  // K*CAP ints = 17.6 MB
    unsigned char* gbufS = (unsigned char*)h1 + (size_t)K * CAP * 4;  // 4.4 MB

    hipMemsetAsync(gcurD, 0, sizeof(int) * 1600, stream);  // gcurD + gcurS

    const int PB = (E + TILE - 1) / TILE;

    part_kernel<<<PB, 256, 0, stream>>>(src, dst, gcurD, gcurS, gbufD, gbufS, E, K);
    fillS_kernel<<<K, 256, 0, stream>>>(gcurS, gbufS, nsrc, N, K);
    fillD_kernel<<<K, 256, 0, stream>>>(gcurD, gbufD, csr_src, rowstart, indeg_i, ndst, N, K);

    gemm1_kernel<<<(N + 127) / 128, 256, 0, stream>>>(feat, W1, nsrc, (unsigned short*)h1, N);
    agg1_kernel<<<(N + 63) / 64, 256, 0, stream>>>(csr_src, rowstart, indeg_i, h1, ndst, nsrc, b1, x1s, N);
    agg2f_kernel<<<(N + 63) / 64, 256, 0, stream>>>(csr_src, rowstart, indeg_i, x1s, ndst, W2, b2, out, N);
}

// Round 6
// 430.807 us; speedup vs baseline: 3.9279x; 1.0437x over previous
//
#include <hip/hip_runtime.h>
#include <hip/hip_bf16.h>
#include <math.h>

#define BSHIFT 7                 // 128 nodes per bucket
#define NBUCK(N) (((N) + 127) >> 7)
#define TILE 8192                // edges per partition block (R0 proven: 103 us)
#define CAP 5632                 // max edges/bucket (mean 4224, sd ~65 -> ~21 sigma)

typedef short bf16x8 __attribute__((ext_vector_type(8)));
typedef float f32x16 __attribute__((ext_vector_type(16)));

// ---- bf16 helpers ---------------------------------------------------------
__device__ __forceinline__ unsigned short f2bf(float f) {
    unsigned u = __float_as_uint(f);
    u += 0x7fffu + ((u >> 16) & 1u);      // RNE
    return (unsigned short)(u >> 16);
}
__device__ __forceinline__ unsigned packbf2(float lo, float hi) {
    return (unsigned)f2bf(lo) | ((unsigned)f2bf(hi) << 16);
}
__device__ __forceinline__ float bf_lo(unsigned u) { return __uint_as_float(u << 16); }
__device__ __forceinline__ float bf_hi(unsigned u) { return __uint_as_float(u & 0xffff0000u); }

// ---- pg: part (blocks < PB) fused with gemm1 (blocks >= PB) ---------------
// part is latency/transaction-bound with ALL pipes idle (VALU 2%, HBM 22%,
// occ 13.8%, 403 blocks -> 1.6/CU): gemm1 is the only graph-independent
// phase, so its waves backfill the empty CU slots and run under part's
// latency shadow. gemm1's nsrc epilogue scale moved to agg1 (per-edge fp32
// multiply, math-identical) so gemm needs nothing from the pipeline.
__global__ __launch_bounds__(256) void pg_kernel(
    const int* __restrict__ src, const int* __restrict__ dst,
    int* __restrict__ gcurD, int* __restrict__ gcurS,
    int* __restrict__ gbufD, unsigned char* __restrict__ gbufS,
    const float* __restrict__ feat, const float* __restrict__ W1,
    unsigned short* __restrict__ h1, int E, int K, int PB, int N) {
    __shared__ char smem[16896];   // max(part 12.8 KB, gemm W1t 16.9 KB)
    const int t = threadIdx.x;

    if (blockIdx.x < PB) {
        // ---------------- part body (EXACT R0 form, 103 us) ----------------
        int* cD = (int*)smem;
        int* bD = cD + 800;
        int* cS = bD + 800;
        int* bS = cS + 800;        // 3200 ints = 12.8 KB
        const int tile = blockIdx.x * TILE;
        for (int i = t; i < K; i += 256) { cD[i] = 0; cS[i] = 0; }
        __syncthreads();

        int dv[32];
        #pragma unroll
        for (int i = 0; i < 32; ++i) {
            const int e = tile + i * 256 + t;
            dv[i] = (e < E) ? dst[e] : -1;
            if (dv[i] >= 0) {
                atomicAdd(&cD[dv[i] >> BSHIFT], 1);
                atomicAdd(&cS[src[e] >> BSHIFT], 1);
            }
        }
        __syncthreads();
        for (int i = t; i < K; i += 256) {
            int c = cD[i];
            bD[i] = (c ? atomicAdd(&gcurD[i], c) : 0) + i * CAP;
            cD[i] = 0;
            c = cS[i];
            bS[i] = (c ? atomicAdd(&gcurS[i], c) : 0) + i * CAP;
            cS[i] = 0;
        }
        __syncthreads();
        #pragma unroll
        for (int i = 0; i < 32; ++i) {
            if (dv[i] >= 0) {
                const int e = tile + i * 256 + t;
                const int sv = src[e];
                const int b1 = dv[i] >> BSHIFT;
                const int p1 = bD[b1] + atomicAdd(&cD[b1], 1);
                gbufD[p1] = ((dv[i] & 127) << 17) | sv;
                const int b2 = sv >> BSHIFT;
                const int p2 = bS[b2] + atomicAdd(&cS[b2], 1);
                gbufS[p2] = (unsigned char)(sv & 127);
            }
        }
    } else {
        // ---------------- gemm1 body (unscaled h1) -------------------------
        short* W1t = (short*)smem;     // W1t[c][k] = bf16(W1[k][c]), stride 264
        for (int i = t; i < 8192; i += 256) {
            const int k = i >> 5, c = i & 31;
            W1t[c * 264 + k] = (short)f2bf(W1[i]);
        }
        __syncthreads();

        const int l  = t & 63;
        const int wv = t >> 6;
        const int base = (blockIdx.x - PB) * 128 + wv * 32;
        const int m  = l & 31;
        const int kh = (l >> 5) << 3;
        int r = base + m;
        if (r >= N) r = N - 1;
        const float* fr = feat + (size_t)r * 256 + kh;
        const short* wr = &W1t[m * 264 + kh];

        f32x16 acc;
        #pragma unroll
        for (int i = 0; i < 16; ++i) acc[i] = 0.f;

        #pragma unroll
        for (int kb = 0; kb < 16; ++kb) {
            const float4 f0 = *(const float4*)(fr + kb * 16);
            const float4 f1 = *(const float4*)(fr + kb * 16 + 4);
            bf16x8 a;
            a[0] = (short)f2bf(f0.x); a[1] = (short)f2bf(f0.y);
            a[2] = (short)f2bf(f0.z); a[3] = (short)f2bf(f0.w);
            a[4] = (short)f2bf(f1.x); a[5] = (short)f2bf(f1.y);
            a[6] = (short)f2bf(f1.z); a[7] = (short)f2bf(f1.w);
            const bf16x8 b = *(const bf16x8*)(wr + kb * 16);
            acc = __builtin_amdgcn_mfma_f32_32x32x16_bf16(a, b, acc, 0, 0, 0);
        }

        const int rbase = base + ((l >> 5) << 2);
        #pragma unroll
        for (int reg = 0; reg < 16; ++reg) {
            const int row = rbase + (reg & 3) + ((reg >> 2) << 3);
            if (row < N)
                h1[(size_t)row * 32 + m] = f2bf(acc[reg]);
        }
    }
}

// ---- fillS: per src-bucket (128 nodes): outdeg -> nsrc --------------------
__global__ __launch_bounds__(256) void fillS_kernel(
    const int* __restrict__ cntS, const unsigned char* __restrict__ gbufS,
    float* __restrict__ nsrc, int N, int K) {
    __shared__ int cnt[128];
    const int t = threadIdx.x;
    const int b = blockIdx.x;
    if (t < 128) cnt[t] = 0;
    __syncthreads();
    const int bs = b * CAP;
    const int be = bs + cntS[b];
    for (int idx = bs + t; idx < be; idx += 256)
        atomicAdd(&cnt[gbufS[idx]], 1);
    __syncthreads();
    const int n = (b << BSHIFT) + t;
    if (t < 128 && n < N) nsrc[n] = rsqrtf((float)cnt[t]);   // self-loops => deg>=1
}

// ---- fillD: per dst-bucket (128 nodes): indeg, rowstart, ndst, CSR --------
__global__ __launch_bounds__(256) void fillD_kernel(
    const int* __restrict__ cntD, const int* __restrict__ gbufD,
    int* __restrict__ csr_src, int* __restrict__ rowstart, int* __restrict__ indeg,
    float* __restrict__ ndst, int N, int K) {
    __shared__ int cnt[128];
    __shared__ int sc[128];
    __shared__ int cur[128];
    const int t = threadIdx.x;
    const int b = blockIdx.x;
    if (t < 128) cnt[t] = 0;
    __syncthreads();
    const int bs = b * CAP;
    const int be = bs + cntD[b];
    for (int idx = bs + t; idx < be; idx += 256)
        atomicAdd(&cnt[gbufD[idx] >> 17], 1);
    __syncthreads();
    if (t < 128) sc[t] = cnt[t];
    __syncthreads();
    for (int off = 1; off < 128; off <<= 1) {
        int x = (t < 128 && t >= off) ? sc[t - off] : 0;
        __syncthreads();
        if (t < 128) sc[t] += x;
        __syncthreads();
    }
    if (t < 128) {
        const int deg = cnt[t];
        const int rs = bs + sc[t] - deg;
        cur[t] = rs;
        const int n = (b << BSHIFT) + t;
        if (n < N) {
            rowstart[n] = rs;
            indeg[n] = deg;
            ndst[n] = rsqrtf((float)deg);   // self-loops => deg >= 1
        }
    }
    __syncthreads();
    for (int idx = bs + t; idx < be; idx += 256) {
        const int p = gbufD[idx];
        const int pos = atomicAdd(&cur[p >> 17], 1);
        csr_src[pos] = p & 131071;
    }
}

// ---- agg1: x1s[n] = bf16( relu(ndst[n]*sum nsrc[s]*h1u[s] + b1) * nsrc[n] )
// h1 now unscaled (gemm fused into pg); nsrc[s] applied per-edge in fp32
// (broadcast 4B load, L2-resident 400KB table). Unroll-2 with dual
// accumulators: 2 gathers in flight per thread (loop was latency-bound on
// the csr->H chain with ~33 serial iterations).
__global__ __launch_bounds__(256) void agg1_kernel(
    const int* __restrict__ csr_src, const int* __restrict__ rowstart,
    const int* __restrict__ indeg, const unsigned* __restrict__ h1,
    const float* __restrict__ ndst, const float* __restrict__ nsrc,
    const float* __restrict__ b1, unsigned* __restrict__ x1s, int N) {
    const int t = threadIdx.x;
    const int n = blockIdx.x * 64 + (t >> 2);
    if (n >= N) return;
    const int c = t & 3;
    const int rs = rowstart[n];
    const int re = rs + indeg[n];
    float a0=0.f,a1=0.f,a2=0.f,a3=0.f,a4=0.f,a5=0.f,a6=0.f,a7=0.f;
    float d0=0.f,d1=0.f,d2=0.f,d3=0.f,d4=0.f,d5=0.f,d6=0.f,d7=0.f;
    const uint4* H = (const uint4*)h1;
    int k = rs;
    for (; k + 1 < re; k += 2) {
        const int s0 = csr_src[k];
        const int s1 = csr_src[k + 1];
        const uint4 q0 = H[(size_t)s0 * 4 + c];
        const uint4 q1 = H[(size_t)s1 * 4 + c];
        const float w0 = nsrc[s0];
        const float w1 = nsrc[s1];
        a0 += bf_lo(q0.x) * w0; a1 += bf_hi(q0.x) * w0;
        a2 += bf_lo(q0.y) * w0; a3 += bf_hi(q0.y) * w0;
        a4 += bf_lo(q0.z) * w0; a5 += bf_hi(q0.z) * w0;
        a6 += bf_lo(q0.w) * w0; a7 += bf_hi(q0.w) * w0;
        d0 += bf_lo(q1.x) * w1; d1 += bf_hi(q1.x) * w1;
        d2 += bf_lo(q1.y) * w1; d3 += bf_hi(q1.y) * w1;
        d4 += bf_lo(q1.z) * w1; d5 += bf_hi(q1.z) * w1;
        d6 += bf_lo(q1.w) * w1; d7 += bf_hi(q1.w) * w1;
    }
    if (k < re) {
        const int s0 = csr_src[k];
        const uint4 q0 = H[(size_t)s0 * 4 + c];
        const float w0 = nsrc[s0];
        a0 += bf_lo(q0.x) * w0; a1 += bf_hi(q0.x) * w0;
        a2 += bf_lo(q0.y) * w0; a3 += bf_hi(q0.y) * w0;
        a4 += bf_lo(q0.z) * w0; a5 += bf_hi(q0.z) * w0;
        a6 += bf_lo(q0.w) * w0; a7 += bf_hi(q0.w) * w0;
    }
    a0 += d0; a1 += d1; a2 += d2; a3 += d3;
    a4 += d4; a5 += d5; a6 += d6; a7 += d7;
    const float nd = ndst[n];
    const float ns = nsrc[n];
    const float* bb = b1 + c * 8;
    float x0 = fmaxf(a0 * nd + bb[0], 0.f) * ns;
    float x1 = fmaxf(a1 * nd + bb[1], 0.f) * ns;
    float x2 = fmaxf(a2 * nd + bb[2], 0.f) * ns;
    float x3 = fmaxf(a3 * nd + bb[3], 0.f) * ns;
    float x4 = fmaxf(a4 * nd + bb[4], 0.f) * ns;
    float x5 = fmaxf(a5 * nd + bb[5], 0.f) * ns;
    float x6 = fmaxf(a6 * nd + bb[6], 0.f) * ns;
    float x7 = fmaxf(a7 * nd + bb[7], 0.f) * ns;
    uint4 o;
    o.x = packbf2(x0, x1); o.y = packbf2(x2, x3);
    o.z = packbf2(x4, x5); o.w = packbf2(x6, x7);
    ((uint4*)x1s)[(size_t)n * 4 + c] = o;
}

// ---- agg2+final fused: z = (ndst[n]*sum x1s[src]) @ W2 + b2; log_softmax --
// Unroll-2 dual accumulators (same MLP rationale as agg1).
__global__ __launch_bounds__(256) void agg2f_kernel(
    const int* __restrict__ csr_src, const int* __restrict__ rowstart,
    const int* __restrict__ indeg, const unsigned* __restrict__ x1s,
    const float* __restrict__ ndst, const float* __restrict__ W2,
    const float* __restrict__ b2, float* __restrict__ out, int N) {
    __shared__ float sW2[32 * 40];
    __shared__ float sb2[40];
    const int t = threadIdx.x;
    for (int i = t; i < 1280; i += 256) sW2[i] = W2[i];
    if (t < 40) sb2[t] = b2[t];
    __syncthreads();
    const int n = blockIdx.x * 64 + (t >> 2);
    if (n >= N) return;
    const int c = t & 3;
    const int rs = rowstart[n];
    const int re = rs + indeg[n];
    float a0=0.f,a1=0.f,a2=0.f,a3=0.f,a4=0.f,a5=0.f,a6=0.f,a7=0.f;
    float d0=0.f,d1=0.f,d2=0.f,d3=0.f,d4=0.f,d5=0.f,d6=0.f,d7=0.f;
    const uint4* H = (const uint4*)x1s;
    int k = rs;
    for (; k + 1 < re; k += 2) {
        const int s0 = csr_src[k];
        const int s1 = csr_src[k + 1];
        const uint4 q0 = H[(size_t)s0 * 4 + c];
        const uint4 q1 = H[(size_t)s1 * 4 + c];
        a0 += bf_lo(q0.x); a1 += bf_hi(q0.x);
        a2 += bf_lo(q0.y); a3 += bf_hi(q0.y);
        a4 += bf_lo(q0.z); a5 += bf_hi(q0.z);
        a6 += bf_lo(q0.w); a7 += bf_hi(q0.w);
        d0 += bf_lo(q1.x); d1 += bf_hi(q1.x);
        d2 += bf_lo(q1.y); d3 += bf_hi(q1.y);
        d4 += bf_lo(q1.z); d5 += bf_hi(q1.z);
        d6 += bf_lo(q1.w); d7 += bf_hi(q1.w);
    }
    if (k < re) {
        const int s0 = csr_src[k];
        const uint4 q0 = H[(size_t)s0 * 4 + c];
        a0 += bf_lo(q0.x); a1 += bf_hi(q0.x);
        a2 += bf_lo(q0.y); a3 += bf_hi(q0.y);
        a4 += bf_lo(q0.z); a5 += bf_hi(q0.z);
        a6 += bf_lo(q0.w); a7 += bf_hi(q0.w);
    }
    a0 += d0; a1 += d1; a2 += d2; a3 += d3;
    a4 += d4; a5 += d5; a6 += d6; a7 += d7;
    const float nd = ndst[n];
    const float v0 = a0 * nd, v1 = a1 * nd, v2 = a2 * nd, v3 = a3 * nd;
    const float v4 = a4 * nd, v5 = a5 * nd, v6 = a6 * nd, v7 = a7 * nd;

    float z[10];
    #pragma unroll
    for (int u = 0; u < 10; ++u) z[u] = sb2[c * 10 + u];
    const int gbase = (t & 63) & ~3;
    #pragma unroll
    for (int cc = 0; cc < 4; ++cc) {
        const int sl = gbase | cc;
        const float w0 = __shfl(v0, sl, 64);
        const float w1 = __shfl(v1, sl, 64);
        const float w2 = __shfl(v2, sl, 64);
        const float w3 = __shfl(v3, sl, 64);
        const float w4 = __shfl(v4, sl, 64);
        const float w5 = __shfl(v5, sl, 64);
        const float w6 = __shfl(v6, sl, 64);
        const float w7 = __shfl(v7, sl, 64);
        const float* Wr = &sW2[(cc * 8) * 40 + c * 10];
        #pragma unroll
        for (int u = 0; u < 10; ++u) {
            z[u] += w0 * Wr[u]       + w1 * Wr[40 + u]  + w2 * Wr[80 + u]  + w3 * Wr[120 + u]
                  + w4 * Wr[160 + u] + w5 * Wr[200 + u] + w6 * Wr[240 + u] + w7 * Wr[280 + u];
        }
    }
    float m = z[0];
    #pragma unroll
    for (int u = 1; u < 10; ++u) m = fmaxf(m, z[u]);
    m = fmaxf(m, __shfl_xor(m, 1, 64));
    m = fmaxf(m, __shfl_xor(m, 2, 64));
    float s = 0.f;
    #pragma unroll
    for (int u = 0; u < 10; ++u) s += __expf(z[u] - m);
    s += __shfl_xor(s, 1, 64);
    s += __shfl_xor(s, 2, 64);
    const float ls = __logf(s);
    float* op = out + (size_t)n * 40 + c * 10;
    #pragma unroll
    for (int u = 0; u < 10; ++u) op[u] = z[u] - m - ls;
}

extern "C" void kernel_launch(void* const* d_in, const int* in_sizes, int n_in,
                              void* d_out, int out_size, void* d_ws, size_t ws_size,
                              hipStream_t stream) {
    const float* feat = (const float*)d_in[0];
    const int*   src  = (const int*)d_in[1];
    const int*   dst  = (const int*)d_in[2];
    const float* W1   = (const float*)d_in[3];
    const float* b1   = (const float*)d_in[4];
    const float* W2   = (const float*)d_in[5];
    const float* b2   = (const float*)d_in[6];
    float* out = (float*)d_out;

    const int N = in_sizes[0] / 256;   // 100000
    const int E = in_sizes[1];         // 3300000
    const int K = NBUCK(N);            // 782 buckets of 128 nodes

    // layout (44.8 MB, same total as proven R0 layout).
    // Overlay lifetimes (pg writes gbufD/gbufS/h1 concurrently!):
    //   gbufD (17.6 MB) -> over [x1s + a2dead] (19.2 MB): x1s first written
    //     by agg1, AFTER fillD finishes reading gbufD.  OK.
    //   gbufS (4.4 MB)  -> over csr_src head: csr first written by fillD,
    //     AFTER fillS finishes reading gbufS.  OK.
    //   h1 is DEDICATED (written by pg gemm blocks during partition).
    char* p = (char*)d_ws;
    float* nsrc = (float*)p;                 p += (size_t)N * 4;        // 400 KB
    float* ndst = (float*)p;                 p += (size_t)N * 4;
    unsigned* h1  = (unsigned*)p;            p += (size_t)N * 64;       // 6.4 MB
    unsigned* x1s = (unsigned*)p;            p += (size_t)N * 64;       // 6.4 MB
    char* a2dead = (char*)p;                 p += (size_t)N * 128;      // 12.8 MB
    int* rowstart = (int*)p;                 p += (size_t)N * 4;
    int* indeg_i  = (int*)p;                 p += (size_t)N * 4;
    int* gcurD    = (int*)p;                 p += 800 * 4;
    int* gcurS    = (int*)p;                 p += 800 * 4;
    int* csr_src  = (int*)p;                 p += (size_t)K * CAP * 4;  // 17.6 MB
    (void)a2dead;
    int* gbufD = (int*)x1s;                       // 17.6 MB over x1s+a2dead
    unsigned char* gbufS = (unsigned char*)csr_src;   // 4.4 MB over csr head

    hipMemsetAsync(gcurD, 0, sizeof(int) * 1600, stream);  // gcurD + gcurS

    const int PB = (E + TILE - 1) / TILE;      // 403 partition blocks
    const int GB = (N + 127) / 128;            // 782 gemm blocks

    pg_kernel<<<PB + GB, 256, 0, stream>>>(src, dst, gcurD, gcurS, gbufD, gbufS,
                                           feat, W1, (unsigned short*)h1, E, K, PB, N);
    fillS_kernel<<<K, 256, 0, stream>>>(gcurS, gbufS, nsrc, N, K);
    fillD_kernel<<<K, 256, 0, stream>>>(gcurD, gbufD, csr_src, rowstart, indeg_i, ndst, N, K);

    agg1_kernel<<<(N + 63) / 64, 256, 0, stream>>>(csr_src, rowstart, indeg_i, h1, ndst, nsrc, b1, x1s, N);
    agg2f_kernel<<<(N + 63) / 64, 256, 0, stream>>>(csr_src, rowstart, indeg_i, x1s, ndst, W2, b2, out, N);
}

// Round 8
// 384.491 us; speedup vs baseline: 4.4011x; 1.1205x over previous
//
#include <hip/hip_runtime.h>
#include <hip/hip_bf16.h>
#include <math.h>

#define BSHIFT 7                 // 128 nodes per bucket
#define NBUCK(N) (((N) + 127) >> 7)
#define TILE 8192                // edges per partition block (R0 proven: 103 us)
#define CAP 5632                 // max edges/bucket (mean 4224, sd ~65 -> ~21 sigma)

typedef short bf16x8 __attribute__((ext_vector_type(8)));
typedef float f32x16 __attribute__((ext_vector_type(16)));

// ---- bf16 helpers ---------------------------------------------------------
__device__ __forceinline__ unsigned short f2bf(float f) {
    unsigned u = __float_as_uint(f);
    u += 0x7fffu + ((u >> 16) & 1u);      // RNE
    return (unsigned short)(u >> 16);
}
__device__ __forceinline__ unsigned packbf2(float lo, float hi) {
    return (unsigned)f2bf(lo) | ((unsigned)f2bf(hi) << 16);
}
__device__ __forceinline__ float bf_lo(unsigned u) { return __uint_as_float(u << 16); }
__device__ __forceinline__ float bf_hi(unsigned u) { return __uint_as_float(u & 0xffff0000u); }

// ---- pg: part (blocks < PB) fused with gemm1 (blocks >= PB) ---------------
// part is latency/transaction-bound with ALL pipes idle; gemm1 is the only
// graph-independent phase, so its waves backfill the empty CU slots.
__global__ __launch_bounds__(256) void pg_kernel(
    const int* __restrict__ src, const int* __restrict__ dst,
    int* __restrict__ gcurD, int* __restrict__ gcurS,
    int* __restrict__ gbufD, unsigned char* __restrict__ gbufS,
    const float* __restrict__ feat, const float* __restrict__ W1,
    unsigned short* __restrict__ h1, int E, int K, int PB, int N) {
    __shared__ char smem[16896];   // max(part 12.8 KB, gemm W1t 16.9 KB)
    const int t = threadIdx.x;

    if (blockIdx.x < PB) {
        // ---------------- part body (EXACT R0 form, 103 us) ----------------
        int* cD = (int*)smem;
        int* bD = cD + 800;
        int* cS = bD + 800;
        int* bS = cS + 800;        // 3200 ints = 12.8 KB
        const int tile = blockIdx.x * TILE;
        for (int i = t; i < K; i += 256) { cD[i] = 0; cS[i] = 0; }
        __syncthreads();

        int dv[32];
        #pragma unroll
        for (int i = 0; i < 32; ++i) {
            const int e = tile + i * 256 + t;
            dv[i] = (e < E) ? dst[e] : -1;
            if (dv[i] >= 0) {
                atomicAdd(&cD[dv[i] >> BSHIFT], 1);
                atomicAdd(&cS[src[e] >> BSHIFT], 1);
            }
        }
        __syncthreads();
        for (int i = t; i < K; i += 256) {
            int c = cD[i];
            bD[i] = (c ? atomicAdd(&gcurD[i], c) : 0) + i * CAP;
            cD[i] = 0;
            c = cS[i];
            bS[i] = (c ? atomicAdd(&gcurS[i], c) : 0) + i * CAP;
            cS[i] = 0;
        }
        __syncthreads();
        #pragma unroll
        for (int i = 0; i < 32; ++i) {
            if (dv[i] >= 0) {
                const int e = tile + i * 256 + t;
                const int sv = src[e];
                const int b1 = dv[i] >> BSHIFT;
                const int p1 = bD[b1] + atomicAdd(&cD[b1], 1);
                gbufD[p1] = ((dv[i] & 127) << 17) | sv;
                const int b2 = sv >> BSHIFT;
                const int p2 = bS[b2] + atomicAdd(&cS[b2], 1);
                gbufS[p2] = (unsigned char)(sv & 127);
            }
        }
    } else {
        // ---------------- gemm1 body (unscaled h1) -------------------------
        short* W1t = (short*)smem;     // W1t[c][k] = bf16(W1[k][c]), stride 264
        for (int i = t; i < 8192; i += 256) {
            const int k = i >> 5, c = i & 31;
            W1t[c * 264 + k] = (short)f2bf(W1[i]);
        }
        __syncthreads();

        const int l  = t & 63;
        const int wv = t >> 6;
        const int base = (blockIdx.x - PB) * 128 + wv * 32;
        const int m  = l & 31;
        const int kh = (l >> 5) << 3;
        int r = base + m;
        if (r >= N) r = N - 1;
        const float* fr = feat + (size_t)r * 256 + kh;
        const short* wr = &W1t[m * 264 + kh];

        f32x16 acc;
        #pragma unroll
        for (int i = 0; i < 16; ++i) acc[i] = 0.f;

        #pragma unroll
        for (int kb = 0; kb < 16; ++kb) {
            const float4 f0 = *(const float4*)(fr + kb * 16);
            const float4 f1 = *(const float4*)(fr + kb * 16 + 4);
            bf16x8 a;
            a[0] = (short)f2bf(f0.x); a[1] = (short)f2bf(f0.y);
            a[2] = (short)f2bf(f0.z); a[3] = (short)f2bf(f0.w);
            a[4] = (short)f2bf(f1.x); a[5] = (short)f2bf(f1.y);
            a[6] = (short)f2bf(f1.z); a[7] = (short)f2bf(f1.w);
            const bf16x8 b = *(const bf16x8*)(wr + kb * 16);
            acc = __builtin_amdgcn_mfma_f32_32x32x16_bf16(a, b, acc, 0, 0, 0);
        }

        const int rbase = base + ((l >> 5) << 2);
        #pragma unroll
        for (int reg = 0; reg < 16; ++reg) {
            const int row = rbase + (reg & 3) + ((reg >> 2) << 3);
            if (row < N)
                h1[(size_t)row * 32 + m] = f2bf(acc[reg]);
        }
    }
}

// ---- fillS: per src-bucket (128 nodes): outdeg -> nsrc --------------------
__global__ __launch_bounds__(256) void fillS_kernel(
    const int* __restrict__ cntS, const unsigned char* __restrict__ gbufS,
    float* __restrict__ nsrc, int N, int K) {
    __shared__ int cnt[128];
    const int t = threadIdx.x;
    const int b = blockIdx.x;
    if (t < 128) cnt[t] = 0;
    __syncthreads();
    const int bs = b * CAP;
    const int be = bs + min(cntS[b], CAP);
    for (int idx = bs + t; idx < be; idx += 256)
        atomicAdd(&cnt[gbufS[idx]], 1);
    __syncthreads();
    const int n = (b << BSHIFT) + t;
    if (t < 128 && n < N) nsrc[n] = rsqrtf((float)cnt[t]);   // self-loops => deg>=1
}

// ---- fda1: fillD + agg1 fused, one 512-thread block per dst-bucket --------
// The bucket's whole edge segment (<=22.5 KB) fits in LDS: load once,
// count/scan/scatter entirely in LDS, dump sorted CSR back IN PLACE over the
// gbufD segment (coalesced; safe -- this block is its only reader and all
// reads precede the dump), then aggregate directly from LDS-resident CSR.
// Deletes: fillD dispatch, gbufD re-read, csr global read, scattered csr
// writes. Keeps R4's lesson: sort first, no dependent gbufD->H chain.
// agg gather: 4 lanes/node x 128 nodes = 512 thr, unroll-4 (4 gathers in
// flight -- the loop is latency-bound, ~33 serial trips at ~200-900 cy).
__global__ __launch_bounds__(512) void fda1_kernel(
    const int* __restrict__ cntD, int* __restrict__ gbufD,
    const unsigned* __restrict__ h1, const float* __restrict__ nsrc,
    const float* __restrict__ b1, int* __restrict__ rowstart,
    int* __restrict__ indeg, float* __restrict__ ndst,
    unsigned* __restrict__ x1s, int N, int K) {
    __shared__ int lraw[CAP];          // 22.5 KB
    __shared__ int lcsr[CAP];          // 22.5 KB
    __shared__ int cnt[128], sc[128], cur[128];
    __shared__ float sb1[32];
    const int t = threadIdx.x;
    const int b = blockIdx.x;
    if (t < 128) cnt[t] = 0;
    if (t >= 128 && t < 160) sb1[t - 128] = b1[t - 128];
    __syncthreads();

    const int bs = b * CAP;
    const int total = min(cntD[b], CAP);   // defensive clamp (LDS bounds)
    for (int i = t; i < total; i += 512) {
        const int v = gbufD[bs + i];
        lraw[i] = v;
        atomicAdd(&cnt[v >> 17], 1);
    }
    __syncthreads();
    if (t < 128) sc[t] = cnt[t];
    __syncthreads();
    for (int off = 1; off < 128; off <<= 1) {
        int x = (t < 128 && t >= off) ? sc[t - off] : 0;
        __syncthreads();
        if (t < 128) sc[t] += x;
        __syncthreads();
    }
    if (t < 128) {
        const int deg = cnt[t];
        cur[t] = sc[t] - deg;          // bucket-local
        const int n = (b << BSHIFT) + t;
        if (n < N) {
            rowstart[n] = bs + sc[t] - deg;
            indeg[n] = deg;
            ndst[n] = rsqrtf((float)deg);   // self-loops => deg >= 1
        }
    }
    __syncthreads();
    for (int i = t; i < total; i += 512) {
        const int v = lraw[i];
        const int pos = atomicAdd(&cur[v >> 17], 1);
        lcsr[pos] = v & 131071;
    }
    __syncthreads();
    // dump sorted CSR for agg2f, in place over this bucket's gbufD segment
    // (coalesced; all gbufD reads of this block are done).
    for (int i = t; i < total; i += 512) gbufD[bs + i] = lcsr[i];

    // ---- agg1 from LDS csr: 4 lanes per node ----
    const int node = t >> 2;
    const int c = t & 3;
    const int n = (b << BSHIFT) + node;
    if (n >= N) return;
    const int deg = cnt[node];
    const int re = sc[node];
    int k = re - deg;
    float a0=0.f,a1=0.f,a2=0.f,a3=0.f,a4=0.f,a5=0.f,a6=0.f,a7=0.f;
    float d0=0.f,d1=0.f,d2=0.f,d3=0.f,d4=0.f,d5=0.f,d6=0.f,d7=0.f;
    const uint4* H = (const uint4*)h1;
    for (; k + 3 < re; k += 4) {
        const int s0 = lcsr[k],     s1 = lcsr[k + 1];
        const int s2 = lcsr[k + 2], s3 = lcsr[k + 3];
        const uint4 q0 = H[(size_t)s0 * 4 + c];
        const uint4 q1 = H[(size_t)s1 * 4 + c];
        const uint4 q2 = H[(size_t)s2 * 4 + c];
        const uint4 q3 = H[(size_t)s3 * 4 + c];
        const float w0 = nsrc[s0], w1 = nsrc[s1];
        const float w2 = nsrc[s2], w3 = nsrc[s3];
        a0 += bf_lo(q0.x)*w0; a1 += bf_hi(q0.x)*w0;
        a2 += bf_lo(q0.y)*w0; a3 += bf_hi(q0.y)*w0;
        a4 += bf_lo(q0.z)*w0; a5 += bf_hi(q0.z)*w0;
        a6 += bf_lo(q0.w)*w0; a7 += bf_hi(q0.w)*w0;
        d0 += bf_lo(q1.x)*w1; d1 += bf_hi(q1.x)*w1;
        d2 += bf_lo(q1.y)*w1; d3 += bf_hi(q1.y)*w1;
        d4 += bf_lo(q1.z)*w1; d5 += bf_hi(q1.z)*w1;
        d6 += bf_lo(q1.w)*w1; d7 += bf_hi(q1.w)*w1;
        a0 += bf_lo(q2.x)*w2; a1 += bf_hi(q2.x)*w2;
        a2 += bf_lo(q2.y)*w2; a3 += bf_hi(q2.y)*w2;
        a4 += bf_lo(q2.z)*w2; a5 += bf_hi(q2.z)*w2;
        a6 += bf_lo(q2.w)*w2; a7 += bf_hi(q2.w)*w2;
        d0 += bf_lo(q3.x)*w3; d1 += bf_hi(q3.x)*w3;
        d2 += bf_lo(q3.y)*w3; d3 += bf_hi(q3.y)*w3;
        d4 += bf_lo(q3.z)*w3; d5 += bf_hi(q3.z)*w3;
        d6 += bf_lo(q3.w)*w3; d7 += bf_hi(q3.w)*w3;
    }
    for (; k < re; ++k) {
        const int s0 = lcsr[k];
        const uint4 q0 = H[(size_t)s0 * 4 + c];
        const float w0 = nsrc[s0];
        a0 += bf_lo(q0.x)*w0; a1 += bf_hi(q0.x)*w0;
        a2 += bf_lo(q0.y)*w0; a3 += bf_hi(q0.y)*w0;
        a4 += bf_lo(q0.z)*w0; a5 += bf_hi(q0.z)*w0;
        a6 += bf_lo(q0.w)*w0; a7 += bf_hi(q0.w)*w0;
    }
    a0 += d0; a1 += d1; a2 += d2; a3 += d3;
    a4 += d4; a5 += d5; a6 += d6; a7 += d7;
    const float nd = rsqrtf((float)deg);
    const float ns = nsrc[n];
    const float* bb = sb1 + c * 8;
    float x0 = fmaxf(a0 * nd + bb[0], 0.f) * ns;
    float x1 = fmaxf(a1 * nd + bb[1], 0.f) * ns;
    float x2 = fmaxf(a2 * nd + bb[2], 0.f) * ns;
    float x3 = fmaxf(a3 * nd + bb[3], 0.f) * ns;
    float x4 = fmaxf(a4 * nd + bb[4], 0.f) * ns;
    float x5 = fmaxf(a5 * nd + bb[5], 0.f) * ns;
    float x6 = fmaxf(a6 * nd + bb[6], 0.f) * ns;
    float x7 = fmaxf(a7 * nd + bb[7], 0.f) * ns;
    uint4 o;
    o.x = packbf2(x0, x1); o.y = packbf2(x2, x3);
    o.z = packbf2(x4, x5); o.w = packbf2(x6, x7);
    ((uint4*)x1s)[(size_t)n * 4 + c] = o;
}

// ---- agg2+final fused: z = (ndst[n]*sum x1s[src]) @ W2 + b2; log_softmax --
// Unroll-4: 4 gathers in flight (loop is gather-latency-bound).
__global__ __launch_bounds__(256) void agg2f_kernel(
    const int* __restrict__ csr_src, const int* __restrict__ rowstart,
    const int* __restrict__ indeg, const unsigned* __restrict__ x1s,
    const float* __restrict__ ndst, const float* __restrict__ W2,
    const float* __restrict__ b2, float* __restrict__ out, int N) {
    __shared__ float sW2[32 * 40];
    __shared__ float sb2[40];
    const int t = threadIdx.x;
    for (int i = t; i < 1280; i += 256) sW2[i] = W2[i];
    if (t < 40) sb2[t] = b2[t];
    __syncthreads();
    const int n = blockIdx.x * 64 + (t >> 2);
    if (n >= N) return;
    const int c = t & 3;
    const int rs = rowstart[n];
    const int re = rs + indeg[n];
    float a0=0.f,a1=0.f,a2=0.f,a3=0.f,a4=0.f,a5=0.f,a6=0.f,a7=0.f;
    float d0=0.f,d1=0.f,d2=0.f,d3=0.f,d4=0.f,d5=0.f,d6=0.f,d7=0.f;
    const uint4* H = (const uint4*)x1s;
    int k = rs;
    for (; k + 3 < re; k += 4) {
        const int s0 = csr_src[k],     s1 = csr_src[k + 1];
        const int s2 = csr_src[k + 2], s3 = csr_src[k + 3];
        const uint4 q0 = H[(size_t)s0 * 4 + c];
        const uint4 q1 = H[(size_t)s1 * 4 + c];
        const uint4 q2 = H[(size_t)s2 * 4 + c];
        const uint4 q3 = H[(size_t)s3 * 4 + c];
        a0 += bf_lo(q0.x); a1 += bf_hi(q0.x);
        a2 += bf_lo(q0.y); a3 += bf_hi(q0.y);
        a4 += bf_lo(q0.z); a5 += bf_hi(q0.z);
        a6 += bf_lo(q0.w); a7 += bf_hi(q0.w);
        d0 += bf_lo(q1.x); d1 += bf_hi(q1.x);
        d2 += bf_lo(q1.y); d3 += bf_hi(q1.y);
        d4 += bf_lo(q1.z); d5 += bf_hi(q1.z);
        d6 += bf_lo(q1.w); d7 += bf_hi(q1.w);
        a0 += bf_lo(q2.x); a1 += bf_hi(q2.x);
        a2 += bf_lo(q2.y); a3 += bf_hi(q2.y);
        a4 += bf_lo(q2.z); a5 += bf_hi(q2.z);
        a6 += bf_lo(q2.w); a7 += bf_hi(q2.w);
        d0 += bf_lo(q3.x); d1 += bf_hi(q3.x);
        d2 += bf_lo(q3.y); d3 += bf_hi(q3.y);
        d4 += bf_lo(q3.z); d5 += bf_hi(q3.z);
        d6 += bf_lo(q3.w); d7 += bf_hi(q3.w);
    }
    for (; k < re; ++k) {
        const int s0 = csr_src[k];
        const uint4 q0 = H[(size_t)s0 * 4 + c];
        a0 += bf_lo(q0.x); a1 += bf_hi(q0.x);
        a2 += bf_lo(q0.y); a3 += bf_hi(q0.y);
        a4 += bf_lo(q0.z); a5 += bf_hi(q0.z);
        a6 += bf_lo(q0.w); a7 += bf_hi(q0.w);
    }
    a0 += d0; a1 += d1; a2 += d2; a3 += d3;
    a4 += d4; a5 += d5; a6 += d6; a7 += d7;
    const float nd = ndst[n];
    const float v0 = a0 * nd, v1 = a1 * nd, v2 = a2 * nd, v3 = a3 * nd;
    const float v4 = a4 * nd, v5 = a5 * nd, v6 = a6 * nd, v7 = a7 * nd;

    float z[10];
    #pragma unroll
    for (int u = 0; u < 10; ++u) z[u] = sb2[c * 10 + u];
    const int gbase = (t & 63) & ~3;
    #pragma unroll
    for (int cc = 0; cc < 4; ++cc) {
        const int sl = gbase | cc;
        const float w0 = __shfl(v0, sl, 64);
        const float w1 = __shfl(v1, sl, 64);
        const float w2 = __shfl(v2, sl, 64);
        const float w3 = __shfl(v3, sl, 64);
        const float w4 = __shfl(v4, sl, 64);
        const float w5 = __shfl(v5, sl, 64);
        const float w6 = __shfl(v6, sl, 64);
        const float w7 = __shfl(v7, sl, 64);
        const float* Wr = &sW2[(cc * 8) * 40 + c * 10];
        #pragma unroll
        for (int u = 0; u < 10; ++u) {
            z[u] += w0 * Wr[u]       + w1 * Wr[40 + u]  + w2 * Wr[80 + u]  + w3 * Wr[120 + u]
                  + w4 * Wr[160 + u] + w5 * Wr[200 + u] + w6 * Wr[240 + u] + w7 * Wr[280 + u];
        }
    }
    float m = z[0];
    #pragma unroll
    for (int u = 1; u < 10; ++u) m = fmaxf(m, z[u]);
    m = fmaxf(m, __shfl_xor(m, 1, 64));
    m = fmaxf(m, __shfl_xor(m, 2, 64));
    float s = 0.f;
    #pragma unroll
    for (int u = 0; u < 10; ++u) s += __expf(z[u] - m);
    s += __shfl_xor(s, 1, 64);
    s += __shfl_xor(s, 2, 64);
    const float ls = __logf(s);
    float* op = out + (size_t)n * 40 + c * 10;
    #pragma unroll
    for (int u = 0; u < 10; ++u) op[u] = z[u] - m - ls;
}

extern "C" void kernel_launch(void* const* d_in, const int* in_sizes, int n_in,
                              void* d_out, int out_size, void* d_ws, size_t ws_size,
                              hipStream_t stream) {
    const float* feat = (const float*)d_in[0];
    const int*   src  = (const int*)d_in[1];
    const int*   dst  = (const int*)d_in[2];
    const float* W1   = (const float*)d_in[3];
    const float* b1   = (const float*)d_in[4];
    const float* W2   = (const float*)d_in[5];
    const float* b2   = (const float*)d_in[6];
    float* out = (float*)d_out;

    const int N = in_sizes[0] / 256;   // 100000
    const int E = in_sizes[1];         // 3300000
    const int K = NBUCK(N);            // 782 buckets of 128 nodes

    // layout (44.8 MB). Overlays:
    //   csr_src == gbufD (same region): fda1 reads segment then rewrites it
    //     in place with sorted CSR (sequential within each block). agg2f
    //     reads the sorted version. No other consumer.
    //   gbufS (4.4 MB) -> over dead a2 region (12.8 MB): read only by fillS.
    //   h1, x1s fully dedicated (no overlay hazards).
    char* p = (char*)d_ws;
    float* nsrc = (float*)p;                 p += (size_t)N * 4;        // 400 KB
    float* ndst = (float*)p;                 p += (size_t)N * 4;
    unsigned* h1  = (unsigned*)p;            p += (size_t)N * 64;       // 6.4 MB
    unsigned* x1s = (unsigned*)p;            p += (size_t)N * 64;       // 6.4 MB
    char* a2dead = (char*)p;                 p += (size_t)N * 128;      // 12.8 MB
    int* rowstart = (int*)p;                 p += (size_t)N * 4;
    int* indeg_i  = (int*)p;                 p += (size_t)N * 4;
    int* gcurD    = (int*)p;                 p += 800 * 4;
    int* gcurS    = (int*)p;                 p += 800 * 4;
    int* gbufD    = (int*)p;                 p += (size_t)K * CAP * 4;  // 17.6 MB, becomes csr
    unsigned char* gbufS = (unsigned char*)a2dead;   // 4.4 MB over dead a2

    hipMemsetAsync(gcurD, 0, sizeof(int) * 1600, stream);  // gcurD + gcurS

    const int PB = (E + TILE - 1) / TILE;      // 403 partition blocks
    const int GB = (N + 127) / 128;            // 782 gemm blocks

    pg_kernel<<<PB + GB, 256, 0, stream>>>(src, dst, gcurD, gcurS, gbufD, gbufS,
                                           feat, W1, (unsigned short*)h1, E, K, PB, N);
    fillS_kernel<<<K, 256, 0, stream>>>(gcurS, gbufS, nsrc, N, K);
    fda1_kernel<<<K, 512, 0, stream>>>(gcurD, gbufD, h1, nsrc, b1,
                                       rowstart, indeg_i, ndst, x1s, N, K);
    agg2f_kernel<<<(N + 63) / 64, 256, 0, stream>>>(gbufD, rowstart, indeg_i, x1s, ndst, W2, b2, out, N);
}